// Round 5
// baseline (383.338 us; speedup 1.0000x reference)
//
#include <hip/hip_runtime.h>
#include <math.h>

#define DIM 512
#define KCB 1024
#define BM  64
#define NCH 8            // 8 d-chunks of 64
// ws layout (bytes)
#define CBT_OFF   0u         // CB fp16 pre-swizzled: [2 halves][8 chunks][4096 slots*16B] = 1 MB
#define CNORM_OFF 1048576u   // 4 KB
#define XNORM_OFF 1052672u   // 256 KB
#define HIST_OFF  1314816u   // 4 KB
#define LOSS_OFF  1318912u   // 64 B
#define XO 16                // X fp16 region offset inside d_out (block-owned slabs)

typedef _Float16 half8 __attribute__((ext_vector_type(8)));
typedef float floatx4 __attribute__((ext_vector_type(4)));

// async global->LDS DMA, 16B/lane; LDS dest = wave-uniform base + lane*16
__device__ __forceinline__ void g2l16(const void* g, void* l) {
    __builtin_amdgcn_global_load_lds(
        (const __attribute__((address_space(1))) unsigned int*)g,
        (__attribute__((address_space(3))) unsigned int*)l, 16, 0, 0);
}

// Swizzle: 16B group g of row r stored at p = g ^ (r&7); row stride 128 B.
// Read lane (ln,q): p = (ks*4+q) ^ (ln&7): 2-way bank aliasing = free (m136).
// Linear slot order = DMA-compatible (no padding).

// ---------------- merged prep: X->fp16 swizzled + xnorm | CB->fp16 swizzled + cnorm ----------------
__global__ __launch_bounds__(256) void prep(const float* __restrict__ X,
                                            const float* __restrict__ CB,
                                            char* __restrict__ ob,
                                            char* __restrict__ ws) {
    const int t = threadIdx.x;
    const int w = t >> 6, lane = t & 63;
    const int dc = lane >> 3, g = lane & 7;  // lane covers d = lane*8 .. +7
    const int b = blockIdx.x;
    if (b < 2048) {
        // X: 32 rows per block, 8 per wave
        for (int it = 0; it < 8; ++it) {
            int r = b * 32 + w * 8 + it;
            const float4* src = (const float4*)(X + (size_t)r * DIM);
            float4 v0 = src[lane * 2];
            float4 v1 = src[lane * 2 + 1];
            half8 hh;
            hh[0] = (_Float16)v0.x; hh[1] = (_Float16)v0.y; hh[2] = (_Float16)v0.z; hh[3] = (_Float16)v0.w;
            hh[4] = (_Float16)v1.x; hh[5] = (_Float16)v1.y; hh[6] = (_Float16)v1.z; hh[7] = (_Float16)v1.w;
            int rl = r & 63;
            int slot = rl * 8 + (g ^ (rl & 7));
            *(half8*)(ob + XO + (size_t)(r >> 6) * 131072 + dc * 8192 + slot * 16) = hh;
            float s = v0.x * v0.x + v0.y * v0.y + v0.z * v0.z + v0.w * v0.w
                    + v1.x * v1.x + v1.y * v1.y + v1.z * v1.z + v1.w * v1.w;
#pragma unroll
            for (int off = 32; off > 0; off >>= 1) s += __shfl_xor(s, off);
            if (lane == 0) ((float*)(ws + XNORM_OFF))[r] = s;
        }
    } else {
        int k = (b - 2048) * 4 + w;  // one code per wave
        const float4* src = (const float4*)(CB + (size_t)k * DIM);
        float4 v0 = src[lane * 2];
        float4 v1 = src[lane * 2 + 1];
        half8 hh;
        hh[0] = (_Float16)v0.x; hh[1] = (_Float16)v0.y; hh[2] = (_Float16)v0.z; hh[3] = (_Float16)v0.w;
        hh[4] = (_Float16)v1.x; hh[5] = (_Float16)v1.y; hh[6] = (_Float16)v1.z; hh[7] = (_Float16)v1.w;
        int h = k >> 9, kl = k & 511;
        int slot = kl * 8 + (g ^ (kl & 7));
        *(half8*)(ws + CBT_OFF + (size_t)h * 524288 + (size_t)dc * 65536 + (size_t)slot * 16) = hh;
        float s = v0.x * v0.x + v0.y * v0.y + v0.z * v0.z + v0.w * v0.w
                + v1.x * v1.x + v1.y * v1.y + v1.z * v1.z + v1.w * v1.w;
#pragma unroll
        for (int off = 32; off > 0; off >>= 1) s += __shfl_xor(s, off);
        if (lane == 0) ((float*)(ws + CNORM_OFF))[k] = s;
    }
}

// ---------------- main: fp16 MFMA scores (staggered chunk order) + fused argmin/epilogue ----------------
__global__ __launch_bounds__(256, 2) void vq_main(
    char* __restrict__ ob, const float* __restrict__ CB32,
    const char* __restrict__ ws, int* __restrict__ hist,
    float* __restrict__ loss_acc) {
    extern __shared__ char smem[];
    char* CBs = smem;            // [512 codes][64 halves] swizzled, 64 KB
    char* Xs  = smem + 65536;    // [64 rows][64 halves]  swizzled,  8 KB
    // epilogue overlay (after final sync):
    float* argS = (float*)smem;           // [4][64]
    int*   argI = (int*)(smem + 1024);    // [4][64]
    int*   idxF = (int*)(smem + 2048);    // [64]

    const int t = threadIdx.x;
    const int lane = t & 63;
    const int wu = __builtin_amdgcn_readfirstlane(t >> 6);  // wave id (scalar)
    const int q = lane >> 4, ln = lane & 15;
    const int pg = ln & 7;
    const int rb = blockIdx.x;
    const int rowbase = rb * BM;
    const float* cnorm = (const float*)(ws + CNORM_OFF);
    const float* xnorm = (const float*)(ws + XNORM_OFF);

    float bestS[16];
    int bestI[16];
#pragma unroll
    for (int li = 0; li < 16; ++li) { bestS[li] = 3.0e38f; bestI[li] = 0; }

    for (int hj = 0; hj < 2; ++hj) {
        const int h = (hj + (rb >> 3)) & 1;          // staggered half order
        floatx4 acc[4][8];
#pragma unroll
        for (int ar = 0; ar < 4; ++ar)
#pragma unroll
            for (int bc = 0; bc < 8; ++bc) acc[ar][bc] = (floatx4){0.f, 0.f, 0.f, 0.f};

        for (int dj = 0; dj < NCH; ++dj) {
            const int dc = (dj + rb) & 7;            // staggered chunk order (spreads L2 reads)
            __syncthreads();  // previous chunk's readers done
            // stage X chunk: 512 slots (2 DMA / wave)
#pragma unroll
            for (int i2 = 0; i2 < 2; ++i2) {
                int sb = (i2 * 4 + wu) * 64;
                g2l16(ob + XO + (size_t)rb * 131072 + (size_t)dc * 8192 + (size_t)(sb + lane) * 16,
                      Xs + sb * 16);
            }
            // stage CB half-chunk: 4096 slots (16 DMA / wave)
#pragma unroll
            for (int i = 0; i < 16; ++i) {
                int sb = (i * 4 + wu) * 64;
                g2l16(ws + CBT_OFF + (size_t)h * 524288 + (size_t)dc * 65536 + (size_t)(sb + lane) * 16,
                      CBs + sb * 16);
            }
            __syncthreads();  // implicit vmcnt(0) drain
#pragma unroll
            for (int ks = 0; ks < 2; ++ks) {
                const int sw = ((ks << 2) | q) ^ pg;
                half8 a[4];
#pragma unroll
                for (int ar = 0; ar < 4; ++ar)
                    a[ar] = *(const half8*)(Xs + (ar * 16 + ln) * 128 + sw * 16);
#pragma unroll
                for (int bc = 0; bc < 8; ++bc) {
                    half8 bfr = *(const half8*)(CBs + (wu * 128 + bc * 16 + ln) * 128 + sw * 16);
#pragma unroll
                    for (int ar = 0; ar < 4; ++ar)
                        acc[ar][bc] = __builtin_amdgcn_mfma_f32_16x16x32_f16(a[ar], bfr, acc[ar][bc], 0, 0, 0);
                }
            }
        }
        // fold this half — index-aware compare (visit order is rotated, so
        // lowest-index-on-tie must be enforced explicitly)
#pragma unroll
        for (int bc = 0; bc < 8; ++bc) {
            int col = h * 512 + wu * 128 + bc * 16 + ln;
            float cn = cnorm[col];
#pragma unroll
            for (int ar = 0; ar < 4; ++ar)
#pragma unroll
                for (int r = 0; r < 4; ++r) {
                    float s = fmaf(-2.f, acc[ar][bc][r], cn);
                    int li = ar * 4 + r;
                    if (s < bestS[li] || (s == bestS[li] && col < bestI[li])) {
                        bestS[li] = s; bestI[li] = col;
                    }
                }
        }
    }

    // butterfly across the 16 ln-lanes (lowest index wins ties)
#pragma unroll
    for (int off = 1; off <= 8; off <<= 1)
#pragma unroll
        for (int li = 0; li < 16; ++li) {
            float s2 = __shfl_xor(bestS[li], off);
            int i2 = __shfl_xor(bestI[li], off);
            if (s2 < bestS[li] || (s2 == bestS[li] && i2 < bestI[li])) {
                bestS[li] = s2; bestI[li] = i2;
            }
        }
    __syncthreads();  // all LDS frag reads done before overlay writes
    if (ln == 0) {
#pragma unroll
        for (int li = 0; li < 16; ++li) {
            int row = (li >> 2) * 16 + q * 4 + (li & 3);
            argS[wu * 64 + row] = bestS[li];
            argI[wu * 64 + row] = bestI[li];
        }
    }
    __syncthreads();
    if (t < BM) {  // exactly wave 0
        float s = argS[t];
        int bi = argI[t];
#pragma unroll
        for (int ww = 1; ww < 4; ++ww) {
            float s2 = argS[ww * 64 + t];
            int i2 = argI[ww * 64 + t];
            if (s2 < s || (s2 == s && i2 < bi)) { s = s2; bi = i2; }
        }
        idxF[t] = bi;
        atomicAdd(&hist[bi], 1);
        float l = s + xnorm[rowbase + t];  // ||x - c_best||^2
#pragma unroll
        for (int off = 32; off > 0; off >>= 1) l += __shfl_xor(l, off);
        if (t == 0) atomicAdd(loss_acc, l);
    }
    __syncthreads();
    // gather + write quantized (overwrites this block's own X-fp16 slab only)
    float* outq = (float*)ob + 1;
    for (int m = 0; m < BM; ++m) {
        int bi = idxF[m];
        const float* crow = CB32 + (size_t)bi * DIM;
        float v0 = crow[t];
        float v1 = crow[t + 256];
        size_t base = (size_t)(rowbase + m) * DIM;
        outq[base + t] = v0;
        outq[base + t + 256] = v1;
    }
}

// ---------------- finalize: loss scalar + perplexity ----------------
__global__ __launch_bounds__(256) void finalize_kernel(
    const int* __restrict__ hist, const float* __restrict__ loss_acc,
    float* __restrict__ out, int n_rows, int q_count) {
    __shared__ float wsum[4];
    int t = threadIdx.x;
    float invN = 1.f / (float)n_rows;
    float hsum = 0.f;
    for (int k = t; k < KCB; k += 256) {
        float p = (float)hist[k] * invN;
        hsum += p * logf(p + 1e-10f);
    }
#pragma unroll
    for (int off = 32; off > 0; off >>= 1) hsum += __shfl_xor(hsum, off);
    if ((t & 63) == 0) wsum[t >> 6] = hsum;
    __syncthreads();
    if (t == 0) {
        float H = -(wsum[0] + wsum[1] + wsum[2] + wsum[3]);
        out[0] = loss_acc[0] * (1.25f / (float)q_count);  // q_loss + 0.25*e_loss
        out[1 + q_count] = expf(H);
    }
}

extern "C" void kernel_launch(void* const* d_in, const int* in_sizes, int n_in,
                              void* d_out, int out_size, void* d_ws, size_t ws_size,
                              hipStream_t stream) {
    const float* X = (const float*)d_in[0];
    const float* CB = (const float*)d_in[1];
    char* ob = (char*)d_out;
    char* ws = (char*)d_ws;
    int N = in_sizes[0] / DIM;  // 65536 rows

    hipMemsetAsync(ws + HIST_OFF, 0, 4096 + 64, stream);
    prep<<<2048 + 256, 256, 0, stream>>>(X, CB, ob, ws);

    vq_main<<<N / BM, 256, 73728, stream>>>(ob, CB, ws,
                                            (int*)(ws + HIST_OFF),
                                            (float*)(ws + LOSS_OFF));
    finalize_kernel<<<1, 256, 0, stream>>>((int*)(ws + HIST_OFF),
                                           (float*)(ws + LOSS_OFF),
                                           (float*)d_out, N, N * DIM);
}